// Round 16
// baseline (61.858 us; speedup 1.0000x reference)
//
#include <hip/hip_runtime.h>
#include <math.h>

// Register-resident VQC simulator. One wave64 per FOUR batch elements:
// two independent float2-PACKED chains (a: elems 0,1 / b: elems 2,3),
// gate-level interleaved for ILP. Regime rationale: after r13/r14's VALU->DS
// rebalance, VALUBusy=62%, DS~54% -> dependency-latency bound; a second
// chain fills each chain's exchange-latency bubbles. (r11's ILP4-neutral
// does not apply: that ran at VALUBusy=91%, issue-saturated.)
// a = (lane<<2) | r ; wire w <-> bit P = 7-w. Bits 7..2 = lane bits 5..0.
//
// r14 exchange set (verified):
//   xor-1/2/8 : v_mov_dpp (1 VALU instr)
//   xor-4     : ds_swizzle 0x101F
//   xor-16    : ds_swizzle 0x401F
//   xor-32    : ds_bpermute, addr (lane^32)<<2
//   5-CNOT ring head: fused ds_bpermute (verified r7)
// MLP head parallel: 4 groups of 16 lanes, one tanh/lane, group butterfly.
// RZ phases via complex squaring from cos/sin(phi/2) — NO large-angle trig
// (broken on this toolchain; bisected r3 vs r4). Raw inline-asm permlane
// FORBIDDEN (r9). CRX coefficient-select (exact) + fused tail slot-gather (r12).

typedef float v2f __attribute__((ext_vector_type(2)));

struct Ex { int lane; int bp32; };

__device__ __forceinline__ v2f fma2(v2f a, v2f b, v2f c) {
#if __has_builtin(__builtin_elementwise_fma)
    return __builtin_elementwise_fma(a, b, c);
#else
    v2f r; r.x = __builtin_fmaf(a.x, b.x, c.x); r.y = __builtin_fmaf(a.y, b.y, c.y);
    return r;
#endif
}

template<int CTRL>
__device__ __forceinline__ float dppmov(float v) {
#if __has_builtin(__builtin_amdgcn_mov_dpp)
    return __int_as_float(__builtin_amdgcn_mov_dpp(
        __float_as_int(v), CTRL, 0xF, 0xF, true));
#else
    return __int_as_float(__builtin_amdgcn_update_dpp(
        __float_as_int(v), __float_as_int(v), CTRL, 0xF, 0xF, true));
#endif
}

template<int OFF>
__device__ __forceinline__ float swz(float v) {
    return __int_as_float(__builtin_amdgcn_ds_swizzle(__float_as_int(v), OFF));
}

__device__ __forceinline__ float bperm1(int bp, float v) {
    return __int_as_float(__builtin_amdgcn_ds_bpermute(bp, __float_as_int(v)));
}

// ---- lane xor exchange ----
template<int M>
__device__ __forceinline__ float xs(float v, const Ex& ex) {
    if constexpr (M == 1)       return dppmov<0xB1>(v);    // quad_perm [1,0,3,2]
    else if constexpr (M == 2)  return dppmov<0x4E>(v);    // quad_perm [2,3,0,1]
    else if constexpr (M == 8)  return dppmov<0x128>(v);   // row_ror:8 == xor-8
    else if constexpr (M == 4)  return swz<0x101F>(v);     // xor-4 swizzle
    else if constexpr (M == 16) return swz<0x401F>(v);     // xor-16 swizzle
    else                        return bperm1(ex.bp32, v); // xor-32 bpermute
}

template<int M>
__device__ __forceinline__ v2f xs2(v2f v, const Ex& ex) {
    v2f r; r.x = xs<M>(v.x, ex); r.y = xs<M>(v.y, ex); return r;
}

__device__ __forceinline__ v2f bperm2(int bp, v2f v) {
    v2f r;
    r.x = bperm1(bp, v.x);
    r.y = bperm1(bp, v.y);
    return r;
}

__device__ __forceinline__ v2f sel2(bool c, v2f a, v2f b) {
    v2f r; r.x = c ? a.x : b.x; r.y = c ? a.y : b.y; return r;
}

// ---- per-chain packed coefficients ----
struct Coef {
    v2f CT, ST, NST;                     // RX
    v2f W0R, W0I, W1R, W1I, W2R, W2I;    // RZ slot phases
    v2f NW0I, NW1I, NW2I;
};

// ---- generic 1q RX on amplitude bit P ----
template<int P>
__device__ __forceinline__ void rx_bit_pk(const Ex& ex, v2f (&AR)[4], v2f (&AI)[4],
                                          const Coef& C) {
    if constexpr (P >= 2) {
        constexpr int m = 1 << (P - 2);
        #pragma unroll
        for (int r = 0; r < 4; ++r) {
            v2f PR = xs2<m>(AR[r], ex), PI = xs2<m>(AI[r], ex);
            AR[r] = fma2(C.CT, AR[r], C.ST * PI);    // ct*ar + st*pi
            AI[r] = fma2(C.CT, AI[r], C.NST * PR);   // ct*ai - st*pr
        }
    } else {
        v2f NR[4], NI[4];
        #pragma unroll
        for (int r = 0; r < 4; ++r) {
            const int rp = r ^ (1 << P);
            NR[r] = fma2(C.CT, AR[r], C.ST * AI[rp]);
            NI[r] = fma2(C.CT, AI[r], C.NST * AR[rp]);
        }
        #pragma unroll
        for (int r = 0; r < 4; ++r) { AR[r] = NR[r]; AI[r] = NI[r]; }
    }
}

__device__ __forceinline__ void rz_apply_pk(const Coef& C, v2f (&AR)[4], v2f (&AI)[4]) {
    v2f nr, ni;
    nr = fma2(AR[0], C.W0R, AI[0] * C.NW0I); ni = fma2(AR[0], C.W0I, AI[0] * C.W0R); AR[0] = nr; AI[0] = ni;
    nr = fma2(AR[1], C.W1R, AI[1] * C.NW1I); ni = fma2(AR[1], C.W1I, AI[1] * C.W1R); AR[1] = nr; AI[1] = ni;
    nr = fma2(AR[2], C.W1R, AI[2] * C.NW1I); ni = fma2(AR[2], C.W1I, AI[2] * C.W1R); AR[2] = nr; AI[2] = ni;
    nr = fma2(AR[3], C.W2R, AI[3] * C.NW2I); ni = fma2(AR[3], C.W2I, AI[3] * C.W2R); AR[3] = nr; AI[3] = ni;
}

// ---- generic CNOT (used for <0,7>: compile-time slot ctrl, lane target) ----
template<int PC, int PT>
__device__ __forceinline__ void cnot_bits_pk(const Ex& ex, v2f (&AR)[4], v2f (&AI)[4]) {
    if constexpr (PT >= 2) {
        constexpr int m = 1 << (PT - 2);
        #pragma unroll
        for (int r = 0; r < 4; ++r) {
            bool ctrl;
            if constexpr (PC >= 2) ctrl = (ex.lane >> (PC - 2)) & 1;
            else                   ctrl = (r >> PC) & 1;
            v2f PR = xs2<m>(AR[r], ex), PI = xs2<m>(AI[r], ex);
            AR[r] = sel2(ctrl, PR, AR[r]);
            AI[r] = sel2(ctrl, PI, AI[r]);
        }
    } else {
        v2f NR[4], NI[4];
        #pragma unroll
        for (int r = 0; r < 4; ++r) {
            const int rp = r ^ (1 << PT);
            bool ctrl;
            if constexpr (PC >= 2) ctrl = (ex.lane >> (PC - 2)) & 1;
            else                   ctrl = (r >> PC) & 1;
            NR[r] = sel2(ctrl, AR[rp], AR[r]);
            NI[r] = sel2(ctrl, AI[rp], AI[r]);
        }
        #pragma unroll
        for (int r = 0; r < 4; ++r) { AR[r] = NR[r]; AI[r] = NI[r]; }
    }
}

// ---- CRX with lane control (PC>=2): coefficient-select, NO per-reg selects ----
template<int PC, int PT>
__device__ __forceinline__ void crx_lane_pk(const Ex& ex, float c, float s,
                                            v2f (&AR)[4], v2f (&AI)[4]) {
    static_assert(PC >= 2, "lane control only");
    const bool ctrl = (ex.lane >> (PC - 2)) & 1;
    const float cc = ctrl ? c : 1.f;
    const float ss = ctrl ? s : 0.f;
    const v2f CC  = {cc, cc};
    const v2f SS  = {ss, ss};
    const v2f NSS = {-ss, -ss};
    if constexpr (PT >= 2) {
        constexpr int m = 1 << (PT - 2);
        #pragma unroll
        for (int r = 0; r < 4; ++r) {
            v2f PR = xs2<m>(AR[r], ex), PI = xs2<m>(AI[r], ex);
            AR[r] = fma2(CC, AR[r], SS * PI);
            AI[r] = fma2(CC, AI[r], NSS * PR);
        }
    } else {
        v2f NR[4], NI[4];
        #pragma unroll
        for (int r = 0; r < 4; ++r) {
            const int rp = r ^ (1 << PT);
            NR[r] = fma2(CC, AR[r], SS * AI[rp]);
            NI[r] = fma2(CC, AI[r], NSS * AR[rp]);
        }
        #pragma unroll
        for (int r = 0; r < 4; ++r) { AR[r] = NR[r]; AI[r] = NI[r]; }
    }
}

// ---- CRX with slot control (PC<2): compile-time ctrl, identity slots free ----
template<int PC, int PT>
__device__ __forceinline__ void crx_slot_pk(const Ex& ex, float c, float s,
                                            v2f (&AR)[4], v2f (&AI)[4]) {
    static_assert(PC < 2, "slot control only");
    const v2f C  = {c, c};
    const v2f S  = {s, s};
    const v2f NS = {-s, -s};
    if constexpr (PT >= 2) {
        constexpr int m = 1 << (PT - 2);
        #pragma unroll
        for (int r = 0; r < 4; ++r) {
            if ((r >> PC) & 1) {
                v2f PR = xs2<m>(AR[r], ex), PI = xs2<m>(AI[r], ex);
                AR[r] = fma2(C, AR[r], S * PI);
                AI[r] = fma2(C, AI[r], NS * PR);
            }
        }
    } else {
        v2f NR[4], NI[4];
        #pragma unroll
        for (int r = 0; r < 4; ++r) {
            const int rp = r ^ (1 << PT);
            if ((r >> PC) & 1) {
                NR[r] = fma2(C, AR[r], S * AI[rp]);
                NI[r] = fma2(C, AI[r], NS * AR[rp]);
            } else { NR[r] = AR[r]; NI[r] = AI[r]; }
        }
        #pragma unroll
        for (int r = 0; r < 4; ++r) { AR[r] = NR[r]; AI[r] = NI[r]; }
    }
}

// ---- wave-64 butterfly sum ----
__device__ __forceinline__ float wave_sum(float v, const Ex& ex) {
    v += xs<1>(v, ex);
    v += xs<2>(v, ex);
    v += xs<4>(v, ex);
    v += xs<8>(v, ex);
    v += xs<16>(v, ex);
    v += xs<32>(v, ex);
    return v;
}

// ---- RZ^(x8) phases per element: e^{i*phi*(popc(a)-4)} via complex squaring ----
struct RzPhases { float W0r, W0i, W1r, W1i, W2r, W2i; };

__device__ __forceinline__ RzPhases make_rz(int lane, float zc, float zs) {
    const float c1 = zc * zc - zs * zs,  s1 = 2.f * zc * zs;
    const float c2 = c1 * c1 - s1 * s1,  s2 = 2.f * c1 * s1;
    const float c4 = c2 * c2 - s2 * s2,  s4 = 2.f * c2 * s2;
    const int n = __popc(lane) - 4;
    const int mag = n < 0 ? -n : n;
    float wr = (mag & 1) ? c1 : 1.f;
    float wi = (mag & 1) ? s1 : 0.f;
    {
        const float mr = (mag & 2) ? c2 : 1.f, mi = (mag & 2) ? s2 : 0.f;
        const float tr = wr * mr - wi * mi;
        wi = wr * mi + wi * mr; wr = tr;
    }
    {
        const float mr = (mag & 4) ? c4 : 1.f, mi = (mag & 4) ? s4 : 0.f;
        const float tr = wr * mr - wi * mi;
        wi = wr * mi + wi * mr; wr = tr;
    }
    wi = (n < 0) ? -wi : wi;
    RzPhases P;
    P.W0r = wr; P.W0i = wi;
    P.W1r = wr * c1 - wi * s1;       P.W1i = wr * s1 + wi * c1;
    P.W2r = P.W1r * c1 - P.W1i * s1; P.W2i = P.W1r * s1 + P.W1i * c1;
    return P;
}

__device__ __forceinline__ Coef make_coef(int lane, float2 xv0, float2 xv1) {
    Coef C;
    C.CT  = (v2f){cosf(0.5f * xv0.x),  cosf(0.5f * xv1.x)};
    C.ST  = (v2f){sinf(0.5f * xv0.x),  sinf(0.5f * xv1.x)};
    C.NST = -C.ST;
    const RzPhases Z0 = make_rz(lane, cosf(0.5f * xv0.y), sinf(0.5f * xv0.y));
    const RzPhases Z1 = make_rz(lane, cosf(0.5f * xv1.y), sinf(0.5f * xv1.y));
    C.W0R = (v2f){Z0.W0r, Z1.W0r}; C.W0I = (v2f){Z0.W0i, Z1.W0i};
    C.W1R = (v2f){Z0.W1r, Z1.W1r}; C.W1I = (v2f){Z0.W1i, Z1.W1i};
    C.W2R = (v2f){Z0.W2r, Z1.W2r}; C.W2I = (v2f){Z0.W2i, Z1.W2i};
    C.NW0I = -C.W0I; C.NW1I = -C.W1I; C.NW2I = -C.W2I;
    return C;
}

// ---- prep: wave-invariant CRX trig table into workspace ----
__global__ void vqc_prep_kernel(const float* __restrict__ gt, float* __restrict__ cs) {
    const int i = threadIdx.x;
    if (i < 10) {
        cs[i]      = cosf(0.5f * gt[i]);
        cs[10 + i] = sinf(0.5f * gt[i]);
    }
}

__global__ __launch_bounds__(256) void vqc_reg_kernel(
    const float* __restrict__ x,
    const float* __restrict__ gt,
    const float* __restrict__ W1,
    const float* __restrict__ b1,
    const float* __restrict__ W2,
    const float* __restrict__ b2,
    const float* __restrict__ cs,
    float* __restrict__ out, int Btot)
{
    const int lane = threadIdx.x & 63;
    const int wid  = blockIdx.x * 4 + (threadIdx.x >> 6);
    const int e0 = 4 * wid;

    Ex ex; ex.lane = lane; ex.bp32 = (lane ^ 32) << 2;

    const float2* x2 = (const float2*)x;
    const float2 xv0 = x2[e0     < Btot ? e0     : 0];
    const float2 xv1 = x2[e0 + 1 < Btot ? e0 + 1 : 0];
    const float2 xv2 = x2[e0 + 2 < Btot ? e0 + 2 : 0];
    const float2 xv3 = x2[e0 + 3 < Btot ? e0 + 3 : 0];

    const Coef Ca = make_coef(lane, xv0, xv1);   // chain a: elems 0,1
    const Coef Cb = make_coef(lane, xv2, xv3);   // chain b: elems 2,3

    // Composed lane permutation of the 5 lane-lane CNOTs <7,6>..<3,2> (verified r7)
    int pa = lane;
    pa ^= ((pa >> 1) & 1) << 0;
    pa ^= ((pa >> 2) & 1) << 1;
    pa ^= ((pa >> 3) & 1) << 2;
    pa ^= ((pa >> 4) & 1) << 3;
    pa ^= ((pa >> 5) & 1) << 4;
    const int bp = pa << 2;
    const bool l0 = lane & 1;

    v2f ARa[4], AIa[4], ARb[4], AIb[4];
    #pragma unroll
    for (int r = 0; r < 4; ++r) {
        ARa[r] = (v2f)0.f; AIa[r] = (v2f)0.f;
        ARb[r] = (v2f)0.f; AIb[r] = (v2f)0.f;
    }
    if (lane == 0) { ARa[0] = (v2f){1.f, 1.f}; ARb[0] = (v2f){1.f, 1.f}; }

    #pragma unroll 1
    for (int cyc = 0; cyc < 4; ++cyc) {
        rx_bit_pk<7>(ex, ARa, AIa, Ca);  rx_bit_pk<7>(ex, ARb, AIb, Cb);
        rx_bit_pk<6>(ex, ARa, AIa, Ca);  rx_bit_pk<6>(ex, ARb, AIb, Cb);
        rx_bit_pk<5>(ex, ARa, AIa, Ca);  rx_bit_pk<5>(ex, ARb, AIb, Cb);
        rx_bit_pk<4>(ex, ARa, AIa, Ca);  rx_bit_pk<4>(ex, ARb, AIb, Cb);
        rx_bit_pk<3>(ex, ARa, AIa, Ca);  rx_bit_pk<3>(ex, ARb, AIb, Cb);
        rx_bit_pk<2>(ex, ARa, AIa, Ca);  rx_bit_pk<2>(ex, ARb, AIb, Cb);
        rx_bit_pk<1>(ex, ARa, AIa, Ca);  rx_bit_pk<1>(ex, ARb, AIb, Cb);
        rx_bit_pk<0>(ex, ARa, AIa, Ca);  rx_bit_pk<0>(ex, ARb, AIb, Cb);
        rz_apply_pk(Ca, ARa, AIa);       rz_apply_pk(Cb, ARb, AIb);
        // CNOT ring head (<7,6>..<3,2>): one bpermute per b32
        #pragma unroll
        for (int r = 0; r < 4; ++r) {
            ARa[r] = bperm2(bp, ARa[r]); AIa[r] = bperm2(bp, AIa[r]);
            ARb[r] = bperm2(bp, ARb[r]); AIb[r] = bperm2(bp, AIb[r]);
        }
        // tail <2,1> then <1,0>, fused to one slot gather (both chains):
        // out0=in[l0?2:0]; out1=in[l0?3:1]; out2=in[l0?1:3]; out3=in[l0?0:2]
        {
            v2f nr0 = sel2(l0, ARa[2], ARa[0]), ni0 = sel2(l0, AIa[2], AIa[0]);
            v2f nr1 = sel2(l0, ARa[3], ARa[1]), ni1 = sel2(l0, AIa[3], AIa[1]);
            v2f nr2 = sel2(l0, ARa[1], ARa[3]), ni2 = sel2(l0, AIa[1], AIa[3]);
            v2f nr3 = sel2(l0, ARa[0], ARa[2]), ni3 = sel2(l0, AIa[0], AIa[2]);
            ARa[0] = nr0; AIa[0] = ni0; ARa[1] = nr1; AIa[1] = ni1;
            ARa[2] = nr2; AIa[2] = ni2; ARa[3] = nr3; AIa[3] = ni3;
        }
        {
            v2f nr0 = sel2(l0, ARb[2], ARb[0]), ni0 = sel2(l0, AIb[2], AIb[0]);
            v2f nr1 = sel2(l0, ARb[3], ARb[1]), ni1 = sel2(l0, AIb[3], AIb[1]);
            v2f nr2 = sel2(l0, ARb[1], ARb[3]), ni2 = sel2(l0, AIb[1], AIb[3]);
            v2f nr3 = sel2(l0, ARb[0], ARb[2]), ni3 = sel2(l0, AIb[0], AIb[2]);
            ARb[0] = nr0; AIb[0] = ni0; ARb[1] = nr1; AIb[1] = ni1;
            ARb[2] = nr2; AIb[2] = ni2; ARb[3] = nr3; AIb[3] = ni3;
        }
        // tail <0,7>: slots 1,3 exchange on lane bit5 (compile-time ctrl)
        cnot_bits_pk<0, 7>(ex, ARa, AIa);
        cnot_bits_pk<0, 7>(ex, ARb, AIb);
    }

    // 10 CRX gates: trig from prep table (wave-uniform)
    float cg[10], sg[10];
    if (cs) {
        #pragma unroll
        for (int g = 0; g < 10; ++g) { cg[g] = cs[g]; sg[g] = cs[10 + g]; }
    } else {
        #pragma unroll
        for (int g = 0; g < 10; ++g) {
            cg[g] = cosf(0.5f * gt[g]);
            sg[g] = sinf(0.5f * gt[g]);
        }
    }

    crx_lane_pk<7, 6>(ex, cg[0], sg[0], ARa, AIa);  crx_lane_pk<7, 6>(ex, cg[0], sg[0], ARb, AIb);
    crx_lane_pk<6, 5>(ex, cg[1], sg[1], ARa, AIa);  crx_lane_pk<6, 5>(ex, cg[1], sg[1], ARb, AIb);
    crx_lane_pk<5, 4>(ex, cg[2], sg[2], ARa, AIa);  crx_lane_pk<5, 4>(ex, cg[2], sg[2], ARb, AIb);
    crx_lane_pk<4, 3>(ex, cg[3], sg[3], ARa, AIa);  crx_lane_pk<4, 3>(ex, cg[3], sg[3], ARb, AIb);
    crx_lane_pk<3, 2>(ex, cg[4], sg[4], ARa, AIa);  crx_lane_pk<3, 2>(ex, cg[4], sg[4], ARb, AIb);
    crx_lane_pk<2, 1>(ex, cg[5], sg[5], ARa, AIa);  crx_lane_pk<2, 1>(ex, cg[5], sg[5], ARb, AIb);
    crx_slot_pk<1, 0>(ex, cg[6], sg[6], ARa, AIa);  crx_slot_pk<1, 0>(ex, cg[6], sg[6], ARb, AIb);
    crx_slot_pk<0, 7>(ex, cg[7], sg[7], ARa, AIa);  crx_slot_pk<0, 7>(ex, cg[7], sg[7], ARb, AIb);
    crx_lane_pk<7, 6>(ex, cg[8], sg[8], ARa, AIa);  crx_lane_pk<7, 6>(ex, cg[8], sg[8], ARb, AIb);
    crx_lane_pk<6, 5>(ex, cg[9], sg[9], ARa, AIa);  crx_lane_pk<6, 5>(ex, cg[9], sg[9], ARb, AIb);

    // probabilities (packed), then reductions
    const v2f Pa0 = fma2(ARa[0], ARa[0], AIa[0] * AIa[0]);
    const v2f Pa1 = fma2(ARa[1], ARa[1], AIa[1] * AIa[1]);
    const v2f Pa2 = fma2(ARa[2], ARa[2], AIa[2] * AIa[2]);
    const v2f Pa3 = fma2(ARa[3], ARa[3], AIa[3] * AIa[3]);
    const v2f Pb0 = fma2(ARb[0], ARb[0], AIb[0] * AIb[0]);
    const v2f Pb1 = fma2(ARb[1], ARb[1], AIb[1] * AIb[1]);
    const v2f Pb2 = fma2(ARb[2], ARb[2], AIb[2] * AIb[2]);
    const v2f Pb3 = fma2(ARb[3], ARb[3], AIb[3] * AIb[3]);
    const float sgn3 = ((lane >> 2) & 1) ? -1.f : 1.f;

    float e3a0 = wave_sum(sgn3 * (Pa0.x + Pa1.x + Pa2.x + Pa3.x), ex);
    float e7a0 = wave_sum((Pa0.x - Pa1.x) + (Pa2.x - Pa3.x), ex);
    float e3a1 = wave_sum(sgn3 * (Pa0.y + Pa1.y + Pa2.y + Pa3.y), ex);
    float e7a1 = wave_sum((Pa0.y - Pa1.y) + (Pa2.y - Pa3.y), ex);
    float e3b0 = wave_sum(sgn3 * (Pb0.x + Pb1.x + Pb2.x + Pb3.x), ex);
    float e7b0 = wave_sum((Pb0.x - Pb1.x) + (Pb2.x - Pb3.x), ex);
    float e3b1 = wave_sum(sgn3 * (Pb0.y + Pb1.y + Pb2.y + Pb3.y), ex);
    float e7b1 = wave_sum((Pb0.y - Pb1.y) + (Pb2.y - Pb3.y), ex);
    // all e* wave-uniform after wave_sum.

    // MLP head, PARALLEL: group g = lane>>4 handles element e0+g;
    // lanes j=0..9 of each group one tanh each; 16-lane-group butterfly sum.
    {
        const int g = lane >> 4;          // 0..3
        const int j = lane & 15;
        const float fe3 = (g & 2) ? ((g & 1) ? e3b1 : e3b0)
                                  : ((g & 1) ? e3a1 : e3a0);
        const float fe7 = (g & 2) ? ((g & 1) ? e7b1 : e7b0)
                                  : ((g & 1) ? e7a1 : e7a0);
        float contrib = 0.f;
        if (j < 10) {
            const float h = tanhf(W1[2 * j] * fe3 + W1[2 * j + 1] * fe7 + b1[j]);
            contrib = W2[j] * h;
        }
        contrib += xs<1>(contrib, ex);
        contrib += xs<2>(contrib, ex);
        contrib += xs<4>(contrib, ex);
        contrib += xs<8>(contrib, ex);   // group-of-16 total
        const int bo = e0 + g;
        if (j == 0 && bo < Btot)
            out[bo] = 1.0f / (1.0f + expf(-(contrib + b2[0])));
    }
}

extern "C" void kernel_launch(void* const* d_in, const int* in_sizes, int n_in,
                              void* d_out, int out_size, void* d_ws, size_t ws_size,
                              hipStream_t stream) {
    const float* x  = (const float*)d_in[0];
    const float* gt = (const float*)d_in[1];
    const float* W1 = (const float*)d_in[2];
    const float* b1 = (const float*)d_in[3];
    const float* W2 = (const float*)d_in[4];
    const float* b2 = (const float*)d_in[5];
    float* out = (float*)d_out;

    const int Btot  = in_sizes[0] / 2;          // x is (B, 2)
    const int waves = (Btot + 3) / 4;           // 4 elements per wave (2 packed chains)
    const int blocks = (waves + 3) / 4;         // 4 waves per 256-thread block

    float* cs = nullptr;
    if (ws_size >= 20 * sizeof(float)) {
        cs = (float*)d_ws;
        vqc_prep_kernel<<<1, 64, 0, stream>>>(gt, cs);
    }
    vqc_reg_kernel<<<blocks, 256, 0, stream>>>(x, gt, W1, b1, W2, b2, cs, out, Btot);
}

// Round 17
// 59.167 us; speedup vs baseline: 1.0455x; 1.0455x over previous
//
#include <hip/hip_runtime.h>
#include <math.h>

// Register-resident VQC simulator. One wave64 per TWO batch elements, PACKED
// via clang ext_vector float2 (elem0 = .x, elem1 = .y).  [FINAL: r14 revert]
// a = (lane<<2) | r ; wire w <-> bit P = 7-w. Bits 7..2 = lane bits 5..0.
//
// r14 exchange strategy (verified best):
//   xor-1/2/8 : v_mov_dpp (1 VALU instr, no tied-old copy)
//   xor-4     : ds_swizzle 0x101F
//   xor-16    : ds_swizzle 0x401F
//   xor-32    : ds_bpermute, addr (lane^32)<<2
//   5-CNOT ring head: fused ds_bpermute (verified r7)
// MLP head parallelized: lanes 0-9 (elem0) / 16-25 (elem1) one tanh each +
// 16-lane-group butterfly reduce.
// RZ phases via complex squaring from cos/sin(phi/2) — NO large-angle trig
// (broken on this toolchain; bisected r3 vs r4). Raw inline-asm permlane
// FORBIDDEN (r9). CRX coefficient-select (exact) + fused tail slot-gather (r12).
// ILP variants (r11 issue-bound, r15 latency-bound) both null -> 2 elems/wave
// maximizes TLP and is the verified optimum.

typedef float v2f __attribute__((ext_vector_type(2)));

struct Ex { int lane; int bp32; };

__device__ __forceinline__ v2f fma2(v2f a, v2f b, v2f c) {
#if __has_builtin(__builtin_elementwise_fma)
    return __builtin_elementwise_fma(a, b, c);
#else
    v2f r; r.x = __builtin_fmaf(a.x, b.x, c.x); r.y = __builtin_fmaf(a.y, b.y, c.y);
    return r;
#endif
}

template<int CTRL>
__device__ __forceinline__ float dppmov(float v) {
#if __has_builtin(__builtin_amdgcn_mov_dpp)
    return __int_as_float(__builtin_amdgcn_mov_dpp(
        __float_as_int(v), CTRL, 0xF, 0xF, true));
#else
    return __int_as_float(__builtin_amdgcn_update_dpp(
        __float_as_int(v), __float_as_int(v), CTRL, 0xF, 0xF, true));
#endif
}

template<int OFF>
__device__ __forceinline__ float swz(float v) {
    return __int_as_float(__builtin_amdgcn_ds_swizzle(__float_as_int(v), OFF));
}

__device__ __forceinline__ float bperm1(int bp, float v) {
    return __int_as_float(__builtin_amdgcn_ds_bpermute(bp, __float_as_int(v)));
}

// ---- lane xor exchange ----
template<int M>
__device__ __forceinline__ float xs(float v, const Ex& ex) {
    if constexpr (M == 1)       return dppmov<0xB1>(v);    // quad_perm [1,0,3,2]
    else if constexpr (M == 2)  return dppmov<0x4E>(v);    // quad_perm [2,3,0,1]
    else if constexpr (M == 8)  return dppmov<0x128>(v);   // row_ror:8 == xor-8
    else if constexpr (M == 4)  return swz<0x101F>(v);     // xor-4 swizzle
    else if constexpr (M == 16) return swz<0x401F>(v);     // xor-16 swizzle
    else                        return bperm1(ex.bp32, v); // xor-32 bpermute
}

template<int M>
__device__ __forceinline__ v2f xs2(v2f v, const Ex& ex) {
    v2f r; r.x = xs<M>(v.x, ex); r.y = xs<M>(v.y, ex); return r;
}

__device__ __forceinline__ v2f bperm2(int bp, v2f v) {
    v2f r;
    r.x = bperm1(bp, v.x);
    r.y = bperm1(bp, v.y);
    return r;
}

__device__ __forceinline__ v2f sel2(bool c, v2f a, v2f b) {
    v2f r; r.x = c ? a.x : b.x; r.y = c ? a.y : b.y; return r;
}

// ---- per-chain packed coefficients ----
struct Coef {
    v2f CT, ST, NST;                     // RX
    v2f W0R, W0I, W1R, W1I, W2R, W2I;    // RZ slot phases
    v2f NW0I, NW1I, NW2I;
};

// ---- generic 1q RX on amplitude bit P ----
template<int P>
__device__ __forceinline__ void rx_bit_pk(const Ex& ex, v2f (&AR)[4], v2f (&AI)[4],
                                          const Coef& C) {
    if constexpr (P >= 2) {
        constexpr int m = 1 << (P - 2);
        #pragma unroll
        for (int r = 0; r < 4; ++r) {
            v2f PR = xs2<m>(AR[r], ex), PI = xs2<m>(AI[r], ex);
            AR[r] = fma2(C.CT, AR[r], C.ST * PI);    // ct*ar + st*pi
            AI[r] = fma2(C.CT, AI[r], C.NST * PR);   // ct*ai - st*pr
        }
    } else {
        v2f NR[4], NI[4];
        #pragma unroll
        for (int r = 0; r < 4; ++r) {
            const int rp = r ^ (1 << P);
            NR[r] = fma2(C.CT, AR[r], C.ST * AI[rp]);
            NI[r] = fma2(C.CT, AI[r], C.NST * AR[rp]);
        }
        #pragma unroll
        for (int r = 0; r < 4; ++r) { AR[r] = NR[r]; AI[r] = NI[r]; }
    }
}

__device__ __forceinline__ void rz_apply_pk(const Coef& C, v2f (&AR)[4], v2f (&AI)[4]) {
    v2f nr, ni;
    nr = fma2(AR[0], C.W0R, AI[0] * C.NW0I); ni = fma2(AR[0], C.W0I, AI[0] * C.W0R); AR[0] = nr; AI[0] = ni;
    nr = fma2(AR[1], C.W1R, AI[1] * C.NW1I); ni = fma2(AR[1], C.W1I, AI[1] * C.W1R); AR[1] = nr; AI[1] = ni;
    nr = fma2(AR[2], C.W1R, AI[2] * C.NW1I); ni = fma2(AR[2], C.W1I, AI[2] * C.W1R); AR[2] = nr; AI[2] = ni;
    nr = fma2(AR[3], C.W2R, AI[3] * C.NW2I); ni = fma2(AR[3], C.W2I, AI[3] * C.W2R); AR[3] = nr; AI[3] = ni;
}

// ---- generic CNOT (used for <0,7>: compile-time slot ctrl, lane target) ----
template<int PC, int PT>
__device__ __forceinline__ void cnot_bits_pk(const Ex& ex, v2f (&AR)[4], v2f (&AI)[4]) {
    if constexpr (PT >= 2) {
        constexpr int m = 1 << (PT - 2);
        #pragma unroll
        for (int r = 0; r < 4; ++r) {
            bool ctrl;
            if constexpr (PC >= 2) ctrl = (ex.lane >> (PC - 2)) & 1;
            else                   ctrl = (r >> PC) & 1;
            v2f PR = xs2<m>(AR[r], ex), PI = xs2<m>(AI[r], ex);
            AR[r] = sel2(ctrl, PR, AR[r]);
            AI[r] = sel2(ctrl, PI, AI[r]);
        }
    } else {
        v2f NR[4], NI[4];
        #pragma unroll
        for (int r = 0; r < 4; ++r) {
            const int rp = r ^ (1 << PT);
            bool ctrl;
            if constexpr (PC >= 2) ctrl = (ex.lane >> (PC - 2)) & 1;
            else                   ctrl = (r >> PC) & 1;
            NR[r] = sel2(ctrl, AR[rp], AR[r]);
            NI[r] = sel2(ctrl, AI[rp], AI[r]);
        }
        #pragma unroll
        for (int r = 0; r < 4; ++r) { AR[r] = NR[r]; AI[r] = NI[r]; }
    }
}

// ---- CRX with lane control (PC>=2): coefficient-select, NO per-reg selects ----
template<int PC, int PT>
__device__ __forceinline__ void crx_lane_pk(const Ex& ex, float c, float s,
                                            v2f (&AR)[4], v2f (&AI)[4]) {
    static_assert(PC >= 2, "lane control only");
    const bool ctrl = (ex.lane >> (PC - 2)) & 1;
    const float cc = ctrl ? c : 1.f;
    const float ss = ctrl ? s : 0.f;
    const v2f CC  = {cc, cc};
    const v2f SS  = {ss, ss};
    const v2f NSS = {-ss, -ss};
    if constexpr (PT >= 2) {
        constexpr int m = 1 << (PT - 2);
        #pragma unroll
        for (int r = 0; r < 4; ++r) {
            v2f PR = xs2<m>(AR[r], ex), PI = xs2<m>(AI[r], ex);
            AR[r] = fma2(CC, AR[r], SS * PI);
            AI[r] = fma2(CC, AI[r], NSS * PR);
        }
    } else {
        v2f NR[4], NI[4];
        #pragma unroll
        for (int r = 0; r < 4; ++r) {
            const int rp = r ^ (1 << PT);
            NR[r] = fma2(CC, AR[r], SS * AI[rp]);
            NI[r] = fma2(CC, AI[r], NSS * AR[rp]);
        }
        #pragma unroll
        for (int r = 0; r < 4; ++r) { AR[r] = NR[r]; AI[r] = NI[r]; }
    }
}

// ---- CRX with slot control (PC<2): compile-time ctrl, identity slots free ----
template<int PC, int PT>
__device__ __forceinline__ void crx_slot_pk(const Ex& ex, float c, float s,
                                            v2f (&AR)[4], v2f (&AI)[4]) {
    static_assert(PC < 2, "slot control only");
    const v2f C  = {c, c};
    const v2f S  = {s, s};
    const v2f NS = {-s, -s};
    if constexpr (PT >= 2) {
        constexpr int m = 1 << (PT - 2);
        #pragma unroll
        for (int r = 0; r < 4; ++r) {
            if ((r >> PC) & 1) {
                v2f PR = xs2<m>(AR[r], ex), PI = xs2<m>(AI[r], ex);
                AR[r] = fma2(C, AR[r], S * PI);
                AI[r] = fma2(C, AI[r], NS * PR);
            }
        }
    } else {
        v2f NR[4], NI[4];
        #pragma unroll
        for (int r = 0; r < 4; ++r) {
            const int rp = r ^ (1 << PT);
            if ((r >> PC) & 1) {
                NR[r] = fma2(C, AR[r], S * AI[rp]);
                NI[r] = fma2(C, AI[r], NS * AR[rp]);
            } else { NR[r] = AR[r]; NI[r] = AI[r]; }
        }
        #pragma unroll
        for (int r = 0; r < 4; ++r) { AR[r] = NR[r]; AI[r] = NI[r]; }
    }
}

// ---- wave-64 butterfly sum ----
__device__ __forceinline__ float wave_sum(float v, const Ex& ex) {
    v += xs<1>(v, ex);
    v += xs<2>(v, ex);
    v += xs<4>(v, ex);
    v += xs<8>(v, ex);
    v += xs<16>(v, ex);
    v += xs<32>(v, ex);
    return v;
}

// ---- RZ^(x8) phases per element: e^{i*phi*(popc(a)-4)} via complex squaring ----
struct RzPhases { float W0r, W0i, W1r, W1i, W2r, W2i; };

__device__ __forceinline__ RzPhases make_rz(int lane, float zc, float zs) {
    const float c1 = zc * zc - zs * zs,  s1 = 2.f * zc * zs;
    const float c2 = c1 * c1 - s1 * s1,  s2 = 2.f * c1 * s1;
    const float c4 = c2 * c2 - s2 * s2,  s4 = 2.f * c2 * s2;
    const int n = __popc(lane) - 4;
    const int mag = n < 0 ? -n : n;
    float wr = (mag & 1) ? c1 : 1.f;
    float wi = (mag & 1) ? s1 : 0.f;
    {
        const float mr = (mag & 2) ? c2 : 1.f, mi = (mag & 2) ? s2 : 0.f;
        const float tr = wr * mr - wi * mi;
        wi = wr * mi + wi * mr; wr = tr;
    }
    {
        const float mr = (mag & 4) ? c4 : 1.f, mi = (mag & 4) ? s4 : 0.f;
        const float tr = wr * mr - wi * mi;
        wi = wr * mi + wi * mr; wr = tr;
    }
    wi = (n < 0) ? -wi : wi;
    RzPhases P;
    P.W0r = wr; P.W0i = wi;
    P.W1r = wr * c1 - wi * s1;       P.W1i = wr * s1 + wi * c1;
    P.W2r = P.W1r * c1 - P.W1i * s1; P.W2i = P.W1r * s1 + P.W1i * c1;
    return P;
}

__device__ __forceinline__ Coef make_coef(int lane, float2 xv0, float2 xv1) {
    Coef C;
    C.CT  = (v2f){cosf(0.5f * xv0.x),  cosf(0.5f * xv1.x)};
    C.ST  = (v2f){sinf(0.5f * xv0.x),  sinf(0.5f * xv1.x)};
    C.NST = -C.ST;
    const RzPhases Z0 = make_rz(lane, cosf(0.5f * xv0.y), sinf(0.5f * xv0.y));
    const RzPhases Z1 = make_rz(lane, cosf(0.5f * xv1.y), sinf(0.5f * xv1.y));
    C.W0R = (v2f){Z0.W0r, Z1.W0r}; C.W0I = (v2f){Z0.W0i, Z1.W0i};
    C.W1R = (v2f){Z0.W1r, Z1.W1r}; C.W1I = (v2f){Z0.W1i, Z1.W1i};
    C.W2R = (v2f){Z0.W2r, Z1.W2r}; C.W2I = (v2f){Z0.W2i, Z1.W2i};
    C.NW0I = -C.W0I; C.NW1I = -C.W1I; C.NW2I = -C.W2I;
    return C;
}

// ---- prep: wave-invariant CRX trig table into workspace ----
__global__ void vqc_prep_kernel(const float* __restrict__ gt, float* __restrict__ cs) {
    const int i = threadIdx.x;
    if (i < 10) {
        cs[i]      = cosf(0.5f * gt[i]);
        cs[10 + i] = sinf(0.5f * gt[i]);
    }
}

__global__ __launch_bounds__(256) void vqc_reg_kernel(
    const float* __restrict__ x,
    const float* __restrict__ gt,
    const float* __restrict__ W1,
    const float* __restrict__ b1,
    const float* __restrict__ W2,
    const float* __restrict__ b2,
    const float* __restrict__ cs,
    float* __restrict__ out, int Btot)
{
    const int lane = threadIdx.x & 63;
    const int wid  = blockIdx.x * 4 + (threadIdx.x >> 6);
    const int b0 = 2 * wid, b1i = 2 * wid + 1;
    const int bb0 = b0  < Btot ? b0  : 0;
    const int bb1 = b1i < Btot ? b1i : 0;

    Ex ex; ex.lane = lane; ex.bp32 = (lane ^ 32) << 2;

    const float2* x2 = (const float2*)x;
    const float2 xv0 = x2[bb0];
    const float2 xv1 = x2[bb1];
    const Coef C = make_coef(lane, xv0, xv1);

    // Composed lane permutation of the 5 lane-lane CNOTs <7,6>..<3,2> (verified r7)
    int pa = lane;
    pa ^= ((pa >> 1) & 1) << 0;
    pa ^= ((pa >> 2) & 1) << 1;
    pa ^= ((pa >> 3) & 1) << 2;
    pa ^= ((pa >> 4) & 1) << 3;
    pa ^= ((pa >> 5) & 1) << 4;
    const int bp = pa << 2;
    const bool l0 = lane & 1;

    v2f AR[4], AI[4];
    #pragma unroll
    for (int r = 0; r < 4; ++r) { AR[r] = (v2f)0.f; AI[r] = (v2f)0.f; }
    if (lane == 0) AR[0] = (v2f){1.f, 1.f};

    #pragma unroll 1
    for (int cyc = 0; cyc < 4; ++cyc) {
        rx_bit_pk<7>(ex, AR, AI, C);
        rx_bit_pk<6>(ex, AR, AI, C);
        rx_bit_pk<5>(ex, AR, AI, C);
        rx_bit_pk<4>(ex, AR, AI, C);
        rx_bit_pk<3>(ex, AR, AI, C);
        rx_bit_pk<2>(ex, AR, AI, C);
        rx_bit_pk<1>(ex, AR, AI, C);
        rx_bit_pk<0>(ex, AR, AI, C);
        rz_apply_pk(C, AR, AI);
        // CNOT ring head (<7,6>..<3,2>): one bpermute per b32
        #pragma unroll
        for (int r = 0; r < 4; ++r) {
            AR[r] = bperm2(bp, AR[r]);
            AI[r] = bperm2(bp, AI[r]);
        }
        // tail <2,1> then <1,0>, fused to one slot gather:
        // out0=in[l0?2:0]; out1=in[l0?3:1]; out2=in[l0?1:3]; out3=in[l0?0:2]
        {
            v2f nr0 = sel2(l0, AR[2], AR[0]), ni0 = sel2(l0, AI[2], AI[0]);
            v2f nr1 = sel2(l0, AR[3], AR[1]), ni1 = sel2(l0, AI[3], AI[1]);
            v2f nr2 = sel2(l0, AR[1], AR[3]), ni2 = sel2(l0, AI[1], AI[3]);
            v2f nr3 = sel2(l0, AR[0], AR[2]), ni3 = sel2(l0, AI[0], AI[2]);
            AR[0] = nr0; AI[0] = ni0; AR[1] = nr1; AI[1] = ni1;
            AR[2] = nr2; AI[2] = ni2; AR[3] = nr3; AI[3] = ni3;
        }
        // tail <0,7>: slots 1,3 exchange on lane bit5 (compile-time ctrl)
        cnot_bits_pk<0, 7>(ex, AR, AI);
    }

    // 10 CRX gates: trig from prep table (wave-uniform)
    float cg[10], sg[10];
    if (cs) {
        #pragma unroll
        for (int g = 0; g < 10; ++g) { cg[g] = cs[g]; sg[g] = cs[10 + g]; }
    } else {
        #pragma unroll
        for (int g = 0; g < 10; ++g) {
            cg[g] = cosf(0.5f * gt[g]);
            sg[g] = sinf(0.5f * gt[g]);
        }
    }

    crx_lane_pk<7, 6>(ex, cg[0], sg[0], AR, AI);
    crx_lane_pk<6, 5>(ex, cg[1], sg[1], AR, AI);
    crx_lane_pk<5, 4>(ex, cg[2], sg[2], AR, AI);
    crx_lane_pk<4, 3>(ex, cg[3], sg[3], AR, AI);
    crx_lane_pk<3, 2>(ex, cg[4], sg[4], AR, AI);
    crx_lane_pk<2, 1>(ex, cg[5], sg[5], AR, AI);
    crx_slot_pk<1, 0>(ex, cg[6], sg[6], AR, AI);
    crx_slot_pk<0, 7>(ex, cg[7], sg[7], AR, AI);
    crx_lane_pk<7, 6>(ex, cg[8], sg[8], AR, AI);
    crx_lane_pk<6, 5>(ex, cg[9], sg[9], AR, AI);

    // probabilities (packed), then reductions
    const v2f P0 = fma2(AR[0], AR[0], AI[0] * AI[0]);
    const v2f P1 = fma2(AR[1], AR[1], AI[1] * AI[1]);
    const v2f P2 = fma2(AR[2], AR[2], AI[2] * AI[2]);
    const v2f P3 = fma2(AR[3], AR[3], AI[3] * AI[3]);
    const float sgn3 = ((lane >> 2) & 1) ? -1.f : 1.f;
    float e3_0 = wave_sum(sgn3 * (P0.x + P1.x + P2.x + P3.x), ex);
    float e7_0 = wave_sum((P0.x - P1.x) + (P2.x - P3.x), ex);
    float e3_1 = wave_sum(sgn3 * (P0.y + P1.y + P2.y + P3.y), ex);
    float e7_1 = wave_sum((P0.y - P1.y) + (P2.y - P3.y), ex);
    // e*_0 / e*_1 are wave-uniform after wave_sum.

    // MLP head, PARALLEL: lanes 0..9 -> elem0 hidden unit j; lanes 16..25 ->
    // elem1 hidden unit j-16. One tanh per lane, 16-lane-group butterfly sum.
    {
        const bool grp1 = (lane >= 16);
        const int  j    = lane & 15;
        const bool act  = (j < 10) && (lane < 32);
        const float fe3 = grp1 ? e3_1 : e3_0;
        const float fe7 = grp1 ? e7_1 : e7_0;
        float contrib = 0.f;
        if (act) {
            const float h = tanhf(W1[2 * j] * fe3 + W1[2 * j + 1] * fe7 + b1[j]);
            contrib = W2[j] * h;
        }
        contrib += xs<1>(contrib, ex);
        contrib += xs<2>(contrib, ex);
        contrib += xs<4>(contrib, ex);
        contrib += xs<8>(contrib, ex);   // group-of-16 total on every lane of group
        if (lane == 0 && b0 < Btot)
            out[b0]  = 1.0f / (1.0f + expf(-(contrib + b2[0])));
        if (lane == 16 && b1i < Btot)
            out[b1i] = 1.0f / (1.0f + expf(-(contrib + b2[0])));
    }
}

extern "C" void kernel_launch(void* const* d_in, const int* in_sizes, int n_in,
                              void* d_out, int out_size, void* d_ws, size_t ws_size,
                              hipStream_t stream) {
    const float* x  = (const float*)d_in[0];
    const float* gt = (const float*)d_in[1];
    const float* W1 = (const float*)d_in[2];
    const float* b1 = (const float*)d_in[3];
    const float* W2 = (const float*)d_in[4];
    const float* b2 = (const float*)d_in[5];
    float* out = (float*)d_out;

    const int Btot  = in_sizes[0] / 2;          // x is (B, 2)
    const int waves = (Btot + 1) / 2;           // 2 elements per wave (packed)
    const int blocks = (waves + 3) / 4;         // 4 waves per 256-thread block

    float* cs = nullptr;
    if (ws_size >= 20 * sizeof(float)) {
        cs = (float*)d_ws;
        vqc_prep_kernel<<<1, 64, 0, stream>>>(gt, cs);
    }
    vqc_reg_kernel<<<blocks, 256, 0, stream>>>(x, gt, W1, b1, W2, b2, cs, out, Btot);
}